// Round 4
// baseline (982.866 us; speedup 1.0000x reference)
//
#include <hip/hip_runtime.h>

typedef unsigned int u32;
typedef __fp16 h2 __attribute__((ext_vector_type(2)));
typedef _Float16 f16x8 __attribute__((ext_vector_type(8)));
typedef float f32x4 __attribute__((ext_vector_type(4)));

#define BB 16
#define LL 2048
#define DD 64
#define RPB 16           // rows per block (MFMA granularity)
#define NTHREADS 256     // 4 waves
#define NBLK (LL / RPB)  // 128 row-blocks per batch

__device__ __forceinline__ h2 pk(float x, float y) {
#if __has_builtin(__builtin_amdgcn_cvt_pkrtz)
    return __builtin_amdgcn_cvt_pkrtz(x, y);
#else
    h2 r; r.x = (__fp16)x; r.y = (__fp16)y; return r;
#endif
}

union F8U { f16x8 v; h2 p[4]; };
__device__ __forceinline__ f16x8 pack8(float4 a, float4 b) {
    F8U u;
    u.p[0] = pk(a.x, a.y); u.p[1] = pk(a.z, a.w);
    u.p[2] = pk(b.x, b.y); u.p[3] = pk(b.z, b.w);
    return u.v;
}
__device__ __forceinline__ f16x8 pack8s(const float* s) {
    F8U u;
    u.p[0] = pk(s[0], s[1]); u.p[1] = pk(s[2], s[3]);
    u.p[2] = pk(s[4], s[5]); u.p[3] = pk(s[6], s[7]);
    return u.v;
}

#define MFMA(A, B, C) __builtin_amdgcn_mfma_f32_16x16x32_f16((A), (B), (C), 0, 0, 0)

// Score quad for wave-subtile (16 cols) at step t: cols c0w..c0w+15, rows r0+4*o4+i.
// s[i] = (q[r0+rl]·k[c] + q[r0+rl]·e[c+2047-(r0+rl)])/8, masked (-60000) for c>r.
__device__ __forceinline__ void score_quad(
    int t, int wave, int o4, int lc, int r0,
    const float* __restrict__ kb, const float* __restrict__ eb,
    f16x8 qa0, f16x8 qa1, float s[4])
{
    const int c0w = (t << 6) + (wave << 4);

    const float* kr = kb + (size_t)(c0w + lc) * DD + 8 * o4;
    float4 k0 = *(const float4*)(kr);
    float4 k1 = *(const float4*)(kr + 4);
    float4 k2 = *(const float4*)(kr + 32);
    float4 k3 = *(const float4*)(kr + 36);

    const int j0w = c0w + 2032 - r0;                 // >= 0 always
    int er0 = j0w + lc;      if (er0 > LL - 1) er0 = LL - 1;   // clamp: masked-only
    int er1 = j0w + 16 + lc; if (er1 > LL - 1) er1 = LL - 1;
    const float* e0p = eb + (size_t)er0 * DD + 8 * o4;
    const float* e1p = eb + (size_t)er1 * DD + 8 * o4;
    float4 ea0 = *(const float4*)(e0p);
    float4 ea1 = *(const float4*)(e0p + 4);
    float4 ea2 = *(const float4*)(e0p + 32);
    float4 ea3 = *(const float4*)(e0p + 36);
    float4 eb0 = *(const float4*)(e1p);
    float4 eb1 = *(const float4*)(e1p + 4);
    float4 eb2 = *(const float4*)(e1p + 32);
    float4 eb3 = *(const float4*)(e1p + 36);

    f16x8 kf0 = pack8(k0, k1), kf1 = pack8(k2, k3);
    f16x8 ef00 = pack8(ea0, ea1), ef01 = pack8(ea2, ea3);
    f16x8 ef10 = pack8(eb0, eb1), ef11 = pack8(eb2, eb3);

    const f32x4 z = {0.f, 0.f, 0.f, 0.f};
    f32x4 dk = MFMA(qa0, kf0, z);  dk = MFMA(qa1, kf1, dk);
    f32x4 g0 = MFMA(qa0, ef00, z); g0 = MFMA(qa1, ef01, g0);
    f32x4 g1 = MFMA(qa0, ef10, z); g1 = MFMA(qa1, ef11, g1);

    // sheared G gather: G[rl][lj] lives in reg i of lane (o4, lj&15)
#pragma unroll
    for (int i = 0; i < 4; ++i) {
        const int rl  = 4 * o4 + i;
        const int lj  = lc + 15 - rl;                // in [0,30]
        const int src = (o4 << 4) | (lj & 15);
        float ga = __shfl(g0[i], src, 64);
        float gb = __shfl(g1[i], src, 64);
        float gv = (lj < 16) ? ga : gb;
        float sv = (dk[i] + gv) * 0.125f;
        if (c0w + lc > r0 + rl) sv = -60000.f;       // fp16/exp-safe "-inf"
        s[i] = sv;
    }
}

__global__ __launch_bounds__(NTHREADS, 6) void attn_fused(
    const float* __restrict__ qg, const float* __restrict__ kg,
    const float* __restrict__ vg, const float* __restrict__ eg,
    float* __restrict__ out_o, float* __restrict__ out_attn)
{
    // P bounce tiles: [wave][tile-parity][query-row][key] (row stride 24 -> 16B aligned)
    __shared__ __align__(16) __fp16 St[4][2][16][24];   // 6 KB
    __shared__ float Ored[3][16][68];                   // 12.75 KB (O cross-wave reduce)
    __shared__ float mred[16][4], lred[16][4], mfin[16], linvs[16];

    const int tid  = threadIdx.x;
    const int wave = tid >> 6;           // 0..3
    const int lane = tid & 63;
    const int o4   = lane >> 4;          // quarter-wave group
    const int lc   = lane & 15;
    const int b    = blockIdx.x / NBLK;
    const int r0   = (blockIdx.x % NBLK) * RPB;
    const size_t bLL = (size_t)b * LL;

    const float* qb = qg + bLL * DD;
    const float* kb = kg + bLL * DD;
    const float* eb = eg + bLL * DD;
    const float* vb = vg + bLL * DD;

    // ---- zero-fill masked attn columns [r0+16, LL) for our 16 rows (streaming) ----
    {
        const int z0 = r0 + RPB;
        const int nq = (LL - z0) >> 2;
        const float4 z4 = make_float4(0.f, 0.f, 0.f, 0.f);
        for (int ri = 0; ri < RPB; ++ri) {
            float4* zp = (float4*)(out_attn + (bLL + r0 + ri) * LL + z0);
            for (int i = tid; i < nq; i += NTHREADS) zp[i] = z4;
        }
    }

    // ---- Q A-fragments (registers throughout) ----
    f16x8 qa0, qa1;
    {
        const float* qr = qb + (size_t)(r0 + lc) * DD + 8 * o4;
        float4 a0 = *(const float4*)(qr);
        float4 a1 = *(const float4*)(qr + 4);
        float4 b0 = *(const float4*)(qr + 32);
        float4 b1 = *(const float4*)(qr + 36);
        qa0 = pack8(a0, a1);
        qa1 = pack8(b0, b1);
    }

    // wave w owns cols {64t+16w .. +15}; live while c0w <= r0+15
    const int span = r0 + 15 - (wave << 4);
    const int nTw  = (span >= 0) ? ((span >> 6) + 1) : 0;

    // ================= sweep A: online max + sum (registers only) =================
    float mrun[4] = {-60000.f, -60000.f, -60000.f, -60000.f};
    float lrun[4] = {0.f, 0.f, 0.f, 0.f};

    for (int t = 0; t < nTw; ++t) {
        float s[4];
        score_quad(t, wave, o4, lc, r0, kb, eb, qa0, qa1, s);
#pragma unroll
        for (int i = 0; i < 4; ++i) {
            float tm = s[i];
            tm = fmaxf(tm, __shfl_xor(tm, 1, 64));
            tm = fmaxf(tm, __shfl_xor(tm, 2, 64));
            tm = fmaxf(tm, __shfl_xor(tm, 4, 64));
            tm = fmaxf(tm, __shfl_xor(tm, 8, 64));   // row tile-max (uniform in 16-group)
            float mn = fmaxf(mrun[i], tm);
            float sc = __expf(mrun[i] - mn);
            lrun[i] = lrun[i] * sc + __expf(s[i] - mn);
            mrun[i] = mn;
        }
    }
#pragma unroll
    for (int i = 0; i < 4; ++i) {
        float lt = lrun[i];
        lt += __shfl_xor(lt, 1, 64);
        lt += __shfl_xor(lt, 2, 64);
        lt += __shfl_xor(lt, 4, 64);
        lt += __shfl_xor(lt, 8, 64);
        if (lc == 0) { mred[4 * o4 + i][wave] = mrun[i]; lred[4 * o4 + i][wave] = lt; }
    }
    __syncthreads();
    if (tid < RPB) {
        float m = -60000.f;
#pragma unroll
        for (int w = 0; w < 4; ++w) m = fmaxf(m, mred[tid][w]);
        float l = 0.f;
#pragma unroll
        for (int w = 0; w < 4; ++w) l += lred[tid][w] * __expf(mred[tid][w] - m);
        mfin[tid]  = m;
        linvs[tid] = 1.f / l;            // every row has >=1 live col -> l > 0
    }
    __syncthreads();

    float mF[4], iF[4];
#pragma unroll
    for (int i = 0; i < 4; ++i) { mF[i] = mfin[4 * o4 + i]; iF[i] = linvs[4 * o4 + i]; }

    // ================= sweep B: recompute -> normalized attn store + PV =================
    f32x4 oacc[4];                       // O accumulators: [d-chunk]; col=d16+lc, row=4o4+i
#pragma unroll
    for (int dc = 0; dc < 4; ++dc) oacc[dc] = (f32x4){0.f, 0.f, 0.f, 0.f};

#define PV_PAIR(CE, CO) do {                                                       \
        f16x8 pa = *(const f16x8*)&St[wave][o4 >> 1][lc][(o4 & 1) << 3];           \
        const int vbase = (((o4) < 2) ? (CE) : (CO)) + ((o4 & 1) << 3);            \
        _Pragma("unroll")                                                          \
        for (int dc = 0; dc < 4; ++dc) {                                           \
            const float* vp = vb + (size_t)vbase * DD + dc * 16 + lc;              \
            float ve[8];                                                           \
            _Pragma("unroll")                                                      \
            for (int e = 0; e < 8; ++e) ve[e] = vp[(size_t)e * DD];                \
            f16x8 vf = pack8s(ve);                                                 \
            oacc[dc] = MFMA(pa, vf, oacc[dc]);                                     \
        }                                                                          \
    } while (0)

    for (int t = 0; t < nTw; ++t) {
        float s[4];
        score_quad(t, wave, o4, lc, r0, kb, eb, qa0, qa1, s);
        const int c = (t << 6) + (wave << 4) + lc;
        float p[4];
#pragma unroll
        for (int i = 0; i < 4; ++i) {
            p[i] = __expf(s[i] - mF[i]) * iF[i];     // masked cols -> exact 0
            out_attn[(bLL + r0 + 4 * o4 + i) * LL + c] = p[i];
            St[wave][t & 1][4 * o4 + i][lc] = (__fp16)p[i];
        }
        if (t & 1) {
            const int ce = ((t - 1) << 6) + (wave << 4);
            const int co = (t << 6) + (wave << 4);
            PV_PAIR(ce, co);
        }
    }
    if (nTw & 1) {                       // unpaired last tile: zero odd buffer, dummy V rows
#pragma unroll
        for (int i = 0; i < 4; ++i) St[wave][1][4 * o4 + i][lc] = (__fp16)0.f;
        const int ce = ((nTw - 1) << 6) + (wave << 4);
        PV_PAIR(ce, ce);
    }

    // ================= O cross-wave reduction + store =================
    if (wave > 0) {
#pragma unroll
        for (int dc = 0; dc < 4; ++dc)
#pragma unroll
            for (int i = 0; i < 4; ++i)
                Ored[wave - 1][4 * o4 + i][dc * 16 + lc] = oacc[dc][i];
    }
    __syncthreads();
    if (wave == 0) {
#pragma unroll
        for (int dc = 0; dc < 4; ++dc)
#pragma unroll
            for (int i = 0; i < 4; ++i) {
                const int rl = 4 * o4 + i, d = dc * 16 + lc;
                float o = oacc[dc][i] + Ored[0][rl][d] + Ored[1][rl][d] + Ored[2][rl][d];
                out_o[(bLL + r0 + rl) * DD + d] = o;   // already normalized
            }
    }
}

extern "C" void kernel_launch(void* const* d_in, const int* in_sizes, int n_in,
                              void* d_out, int out_size, void* d_ws, size_t ws_size,
                              hipStream_t stream) {
    const float* q = (const float*)d_in[0];
    const float* k = (const float*)d_in[1];
    const float* v = (const float*)d_in[2];
    const float* e = (const float*)d_in[3];
    // d_in[4] = mask: causal, deterministic -> unused
    float* out_o    = (float*)d_out;
    float* out_attn = out_o + (size_t)BB * LL * DD;

    dim3 grid(BB * NBLK);
    attn_fused<<<grid, NTHREADS, 0, stream>>>(q, k, v, e, out_o, out_attn);
}

// Round 5
// 812.403 us; speedup vs baseline: 1.2098x; 1.2098x over previous
//
#include <hip/hip_runtime.h>

typedef unsigned int u32;
typedef __fp16 h2 __attribute__((ext_vector_type(2)));
typedef _Float16 f16x8 __attribute__((ext_vector_type(8)));
typedef float f32x4 __attribute__((ext_vector_type(4)));

#define BB 16
#define LL 2048
#define DD 64
#define RPB 16           // rows per block (MFMA granularity)
#define NTHREADS 256     // 4 waves
#define NBLK (LL / RPB)  // 128 row-blocks per batch
#define NWG (BB * NBLK)  // 2048 workgroups, % 8 == 0
#define NXCD 8

__device__ __forceinline__ h2 pk(float x, float y) {
#if __has_builtin(__builtin_amdgcn_cvt_pkrtz)
    return __builtin_amdgcn_cvt_pkrtz(x, y);
#else
    h2 r; r.x = (__fp16)x; r.y = (__fp16)y; return r;
#endif
}

union F8U { f16x8 v; h2 p[4]; };
__device__ __forceinline__ f16x8 pack8(float4 a, float4 b) {
    F8U u;
    u.p[0] = pk(a.x, a.y); u.p[1] = pk(a.z, a.w);
    u.p[2] = pk(b.x, b.y); u.p[3] = pk(b.z, b.w);
    return u.v;
}
__device__ __forceinline__ f16x8 pack8s(const float* s) {
    F8U u;
    u.p[0] = pk(s[0], s[1]); u.p[1] = pk(s[2], s[3]);
    u.p[2] = pk(s[4], s[5]); u.p[3] = pk(s[6], s[7]);
    return u.v;
}

#define MFMA(A, B, C) __builtin_amdgcn_mfma_f32_16x16x32_f16((A), (B), (C), 0, 0, 0)

// Score quad for wave-subtile (16 cols) at step t: cols c0w..c0w+15, rows r0+4*o4+i.
// s[i] = (q[r0+rl]·k[c] + q[r0+rl]·e[c+2047-(r0+rl)])/8, masked (-60000) for c>r.
__device__ __forceinline__ void score_quad(
    int t, int wave, int o4, int lc, int r0,
    const float* __restrict__ kb, const float* __restrict__ eb,
    f16x8 qa0, f16x8 qa1, float s[4])
{
    const int c0w = (t << 6) + (wave << 4);

    const float* kr = kb + (size_t)(c0w + lc) * DD + 8 * o4;
    float4 k0 = *(const float4*)(kr);
    float4 k1 = *(const float4*)(kr + 4);
    float4 k2 = *(const float4*)(kr + 32);
    float4 k3 = *(const float4*)(kr + 36);

    const int j0w = c0w + 2032 - r0;                 // >= 0 always
    int er0 = j0w + lc;      if (er0 > LL - 1) er0 = LL - 1;   // clamp: masked-only
    int er1 = j0w + 16 + lc; if (er1 > LL - 1) er1 = LL - 1;
    const float* e0p = eb + (size_t)er0 * DD + 8 * o4;
    const float* e1p = eb + (size_t)er1 * DD + 8 * o4;
    float4 ea0 = *(const float4*)(e0p);
    float4 ea1 = *(const float4*)(e0p + 4);
    float4 ea2 = *(const float4*)(e0p + 32);
    float4 ea3 = *(const float4*)(e0p + 36);
    float4 eb0 = *(const float4*)(e1p);
    float4 eb1 = *(const float4*)(e1p + 4);
    float4 eb2 = *(const float4*)(e1p + 32);
    float4 eb3 = *(const float4*)(e1p + 36);

    f16x8 kf0 = pack8(k0, k1), kf1 = pack8(k2, k3);
    f16x8 ef00 = pack8(ea0, ea1), ef01 = pack8(ea2, ea3);
    f16x8 ef10 = pack8(eb0, eb1), ef11 = pack8(eb2, eb3);

    const f32x4 z = {0.f, 0.f, 0.f, 0.f};
    f32x4 dk = MFMA(qa0, kf0, z);  dk = MFMA(qa1, kf1, dk);
    f32x4 g0 = MFMA(qa0, ef00, z); g0 = MFMA(qa1, ef01, g0);
    f32x4 g1 = MFMA(qa0, ef10, z); g1 = MFMA(qa1, ef11, g1);

    // sheared G gather: G[rl][lj] lives in reg i of lane (o4, lj&15)
#pragma unroll
    for (int i = 0; i < 4; ++i) {
        const int rl  = 4 * o4 + i;
        const int lj  = lc + 15 - rl;                // in [0,30]
        const int src = (o4 << 4) | (lj & 15);
        float ga = __shfl(g0[i], src, 64);
        float gb = __shfl(g1[i], src, 64);
        float gv = (lj < 16) ? ga : gb;
        float sv = (dk[i] + gv) * 0.125f;
        if (c0w + lc > r0 + rl) sv = -60000.f;       // fp16/exp-safe "-inf"
        s[i] = sv;
    }
}

__global__ __launch_bounds__(NTHREADS, 6) void attn_fused(
    const float* __restrict__ qg, const float* __restrict__ kg,
    const float* __restrict__ vg, const float* __restrict__ eg,
    float* __restrict__ out_o, float* __restrict__ out_attn)
{
    // P bounce tiles: [wave][tile-parity][query-row][key] (row stride 24 -> 16B aligned)
    __shared__ __align__(16) __fp16 St[4][2][16][24];   // 6 KB
    __shared__ float Ored[3][16][68];                   // 12.75 KB (O cross-wave reduce)
    __shared__ float mred[16][4], lred[16][4], mfin[16], linvs[16];

    const int tid  = threadIdx.x;
    const int wave = tid >> 6;           // 0..3
    const int lane = tid & 63;
    const int o4   = lane >> 4;          // quarter-wave group
    const int lc   = lane & 15;

    // XCD-bijective chunk swizzle: hardware sends blockIdx i -> XCD i%8.
    // Remap so each XCD owns 256 CONSECUTIVE logical blocks (= 2 batches):
    // per-XCD L2 working set ~4.5 MB instead of all 16 batches (~24 MB).
    const int work = (blockIdx.x & (NXCD - 1)) * (NWG / NXCD) + (blockIdx.x >> 3);
    const int b    = work / NBLK;
    // LPT within chunk: heavy (large-r0) row-blocks first, light ones drain the tail
    const int r0   = (NBLK - 1 - (work % NBLK)) * RPB;
    const size_t bLL = (size_t)b * LL;

    const float* qb = qg + bLL * DD;
    const float* kb = kg + bLL * DD;
    const float* eb = eg + bLL * DD;
    const float* vb = vg + bLL * DD;

    // ---- zero-fill masked attn columns [r0+16, LL) for our 16 rows (streaming) ----
    {
        const int z0 = r0 + RPB;
        const int nq = (LL - z0) >> 2;
        const float4 z4 = make_float4(0.f, 0.f, 0.f, 0.f);
        for (int ri = 0; ri < RPB; ++ri) {
            float4* zp = (float4*)(out_attn + (bLL + r0 + ri) * LL + z0);
            for (int i = tid; i < nq; i += NTHREADS) zp[i] = z4;
        }
    }

    // ---- Q A-fragments (registers throughout) ----
    f16x8 qa0, qa1;
    {
        const float* qr = qb + (size_t)(r0 + lc) * DD + 8 * o4;
        float4 a0 = *(const float4*)(qr);
        float4 a1 = *(const float4*)(qr + 4);
        float4 b0 = *(const float4*)(qr + 32);
        float4 b1 = *(const float4*)(qr + 36);
        qa0 = pack8(a0, a1);
        qa1 = pack8(b0, b1);
    }

    // wave w owns cols {64t+16w .. +15}; live while c0w <= r0+15
    const int span = r0 + 15 - (wave << 4);
    const int nTw  = (span >= 0) ? ((span >> 6) + 1) : 0;

    // ================= sweep A: online max + sum (registers only) =================
    float mrun[4] = {-60000.f, -60000.f, -60000.f, -60000.f};
    float lrun[4] = {0.f, 0.f, 0.f, 0.f};

    for (int t = 0; t < nTw; ++t) {
        float s[4];
        score_quad(t, wave, o4, lc, r0, kb, eb, qa0, qa1, s);
#pragma unroll
        for (int i = 0; i < 4; ++i) {
            float tm = s[i];
            tm = fmaxf(tm, __shfl_xor(tm, 1, 64));
            tm = fmaxf(tm, __shfl_xor(tm, 2, 64));
            tm = fmaxf(tm, __shfl_xor(tm, 4, 64));
            tm = fmaxf(tm, __shfl_xor(tm, 8, 64));   // row tile-max (uniform in 16-group)
            float mn = fmaxf(mrun[i], tm);
            float sc = __expf(mrun[i] - mn);
            lrun[i] = lrun[i] * sc + __expf(s[i] - mn);
            mrun[i] = mn;
        }
    }
#pragma unroll
    for (int i = 0; i < 4; ++i) {
        float lt = lrun[i];
        lt += __shfl_xor(lt, 1, 64);
        lt += __shfl_xor(lt, 2, 64);
        lt += __shfl_xor(lt, 4, 64);
        lt += __shfl_xor(lt, 8, 64);
        if (lc == 0) { mred[4 * o4 + i][wave] = mrun[i]; lred[4 * o4 + i][wave] = lt; }
    }
    __syncthreads();
    if (tid < RPB) {
        float m = -60000.f;
#pragma unroll
        for (int w = 0; w < 4; ++w) m = fmaxf(m, mred[tid][w]);
        float l = 0.f;
#pragma unroll
        for (int w = 0; w < 4; ++w) l += lred[tid][w] * __expf(mred[tid][w] - m);
        mfin[tid]  = m;
        linvs[tid] = 1.f / l;            // every row has >=1 live col -> l > 0
    }
    __syncthreads();

    float mF[4], iF[4];
#pragma unroll
    for (int i = 0; i < 4; ++i) { mF[i] = mfin[4 * o4 + i]; iF[i] = linvs[4 * o4 + i]; }

    // ================= sweep B: recompute -> normalized attn store + PV =================
    f32x4 oacc[4];                       // O accumulators: [d-chunk]; col=d16+lc, row=4o4+i
#pragma unroll
    for (int dc = 0; dc < 4; ++dc) oacc[dc] = (f32x4){0.f, 0.f, 0.f, 0.f};

#define PV_PAIR(CE, CO) do {                                                       \
        f16x8 pa = *(const f16x8*)&St[wave][o4 >> 1][lc][(o4 & 1) << 3];           \
        const int vbase = (((o4) < 2) ? (CE) : (CO)) + ((o4 & 1) << 3);            \
        _Pragma("unroll")                                                          \
        for (int dc = 0; dc < 4; ++dc) {                                           \
            const float* vp = vb + (size_t)vbase * DD + dc * 16 + lc;              \
            float ve[8];                                                           \
            _Pragma("unroll")                                                      \
            for (int e = 0; e < 8; ++e) ve[e] = vp[(size_t)e * DD];                \
            f16x8 vf = pack8s(ve);                                                 \
            oacc[dc] = MFMA(pa, vf, oacc[dc]);                                     \
        }                                                                          \
    } while (0)

    for (int t = 0; t < nTw; ++t) {
        float s[4];
        score_quad(t, wave, o4, lc, r0, kb, eb, qa0, qa1, s);
        const int c = (t << 6) + (wave << 4) + lc;
        float p[4];
#pragma unroll
        for (int i = 0; i < 4; ++i) {
            p[i] = __expf(s[i] - mF[i]) * iF[i];     // masked cols -> exact 0
            out_attn[(bLL + r0 + 4 * o4 + i) * LL + c] = p[i];
            St[wave][t & 1][4 * o4 + i][lc] = (__fp16)p[i];
        }
        if (t & 1) {
            const int ce = ((t - 1) << 6) + (wave << 4);
            const int co = (t << 6) + (wave << 4);
            PV_PAIR(ce, co);
        }
    }
    if (nTw & 1) {                       // unpaired last tile: zero odd buffer, dummy V rows
#pragma unroll
        for (int i = 0; i < 4; ++i) St[wave][1][4 * o4 + i][lc] = (__fp16)0.f;
        const int ce = ((nTw - 1) << 6) + (wave << 4);
        PV_PAIR(ce, ce);
    }

    // ================= O cross-wave reduction + store =================
    if (wave > 0) {
#pragma unroll
        for (int dc = 0; dc < 4; ++dc)
#pragma unroll
            for (int i = 0; i < 4; ++i)
                Ored[wave - 1][4 * o4 + i][dc * 16 + lc] = oacc[dc][i];
    }
    __syncthreads();
    if (wave == 0) {
#pragma unroll
        for (int dc = 0; dc < 4; ++dc)
#pragma unroll
            for (int i = 0; i < 4; ++i) {
                const int rl = 4 * o4 + i, d = dc * 16 + lc;
                float o = oacc[dc][i] + Ored[0][rl][d] + Ored[1][rl][d] + Ored[2][rl][d];
                out_o[(bLL + r0 + rl) * DD + d] = o;   // already normalized
            }
    }
}

extern "C" void kernel_launch(void* const* d_in, const int* in_sizes, int n_in,
                              void* d_out, int out_size, void* d_ws, size_t ws_size,
                              hipStream_t stream) {
    const float* q = (const float*)d_in[0];
    const float* k = (const float*)d_in[1];
    const float* v = (const float*)d_in[2];
    const float* e = (const float*)d_in[3];
    // d_in[4] = mask: causal, deterministic -> unused
    float* out_o    = (float*)d_out;
    float* out_attn = out_o + (size_t)BB * LL * DD;

    dim3 grid(NWG);
    attn_fused<<<grid, NTHREADS, 0, stream>>>(q, k, v, e, out_o, out_attn);
}